// Round 6
// baseline (3350.700 us; speedup 1.0000x reference)
//
#include <hip/hip_runtime.h>
#include <math.h>

#define N_NEU    4096
#define T_STEPS  2000
#define NTHREADS 1024
#define NPT      4      // neurons per thread
#define NPH      2      // f32x2 pairs per thread
#define NB       16     // replicated blocks; block b writes steps t%NB==b

typedef unsigned int       u32;
typedef unsigned long long u64;
typedef float f32x2 __attribute__((ext_vector_type(2)));

static __device__ __forceinline__ f32x2 mk2(float a, float b) {
    f32x2 r; r[0] = a; r[1] = b; return r;
}

// ---------------------------------------------------------------------------
__global__ void transpose_kernel(const float* __restrict__ W, float* __restrict__ WT)
{
    __shared__ float tile[32][33];
    const int bx = blockIdx.x * 32, by = blockIdx.y * 32;
    const int tx = threadIdx.x, ty = threadIdx.y;
#pragma unroll
    for (int k = 0; k < 32; k += 8)
        tile[ty + k][tx] = W[(size_t)(by + ty + k) * N_NEU + (bx + tx)];
    __syncthreads();
#pragma unroll
    for (int k = 0; k < 32; k += 8)
        WT[(size_t)(bx + ty + k) * N_NEU + (by + tx)] = tile[tx][ty + k];
}

// ---------------------------------------------------------------------------
// Precompute per-step drive terms with ops BIT-IDENTICAL to the in-loop forms:
//   SP[t][n] = stim[t][n] * p02[n]              (f32 mul)
//   D [t][n] = jw0*ext0 + jw1*ext1              (f32 mul,mul,add)
//   DV[t][n] = (f32)((f64)D * (1.0/(f64)ts))    (== no-spike c increment)
// ---------------------------------------------------------------------------
__global__ void prep_kernel(const float* __restrict__ stim,
                            const float* __restrict__ ext,
                            const float* __restrict__ jext,
                            const float* __restrict__ taum,
                            const float* __restrict__ taus,
                            float* __restrict__ SPa,
                            float* __restrict__ Da,
                            float* __restrict__ DVa)
{
#pragma clang fp contract(off)
    const int i = blockIdx.x * 256 + threadIdx.x;   // float4 index, 2048000 total
    const int t = i >> 10, k = i & 1023;
    const float4 s4  = ((const float4*)stim)[i];
    const float4 a4  = ((const float4*)ext)[(size_t)t * 2048 + k];
    const float4 b4  = ((const float4*)ext)[(size_t)t * 2048 + 1024 + k];
    const float4 tm4 = ((const float4*)taum)[k];
    const float4 ts4 = ((const float4*)taus)[k];
    const float jw0 = jext[0], jw1 = jext[1];
    float4 sp, dd, dv;
#define PREP1(F)                                                            \
    {                                                                       \
        const float tm = tm4.F;                                             \
        const float e0 = (float)exp((double)((-1.0e-3f) / tm));             \
        const float p02 = tm * (1.0f - e0);                                 \
        sp.F = s4.F * p02;                                                  \
        dd.F = jw0 * a4.F + jw1 * b4.F;                                     \
        dv.F = (float)((double)dd.F * (1.0 / (double)ts4.F));               \
    }
    PREP1(x) PREP1(y) PREP1(z) PREP1(w)
#undef PREP1
    ((float4*)SPa)[i] = sp;
    ((float4*)Da)[i]  = dd;
    ((float4*)DVa)[i] = dv;
}

// ---------------------------------------------------------------------------
// TIER A: replicated LIF with precomputed drives + wave-uniform fast path.
// R(this): R5's readlane-extraction rotating gather, deepened 3 -> 6 stages.
// Prologue fills 6 named stages (invalid stages re-load column j0's address
// -> L1 hit; neutralized in the drain via fmaf(w in {0,1}) which only
// differs from a plain add when spikes < 6 -- and fmaf(1,x,a)==a+x with one
// rounding, fmaf(0,x,a)==a, so the result is BITWISE identical either way).
// Steady state: extract(scalar pipe) -> issue -> accumulate-oldest under
// vmcnt(5).  Accumulation remains ONE chain in strict ascending neuron
// order.  Everything else unchanged from the validated structure.
// ---------------------------------------------------------------------------
__global__ __launch_bounds__(NTHREADS, 1)
void lifA_kernel(const float* __restrict__ v_init,
                 const float* __restrict__ c_init,
                 const float* __restrict__ SPa,
                 const float* __restrict__ Da,
                 const float* __restrict__ DVa,
                 const float* __restrict__ WT,
                 const float* __restrict__ tau_m_p,
                 const float* __restrict__ tau_s_p,
                 const float* __restrict__ tau_ref_p,
                 const float* __restrict__ thresh_p,
                 const float* __restrict__ reset_p,
                 float* __restrict__ outV,
                 float* __restrict__ outC,
                 float* __restrict__ outS)
{
#pragma clang fp contract(off)
    const int tid  = threadIdx.x;
    const int bid  = blockIdx.x;
    const int n0   = tid * NPT;
    const int lane = tid & 63;

    __shared__ u64 mask64[3][64];
    if (tid < 192) ((u64*)mask64)[tid] = 0ull;

    f32x2 p00[NPH], p01[NPH], p11[NPH], trf[NPH], thv[NPH], rsv[NPH];
    f32x2 v[NPH], c[NPH], tmr[NPH];
    double itau[NPT];

#pragma unroll
    for (int h = 0; h < NPH; ++h) {
#pragma unroll
        for (int e = 0; e < 2; ++e) {
            const int k = 2 * h + e;
            const float tm = tau_m_p[n0 + k], ts = tau_s_p[n0 + k];
            const float a0 = (-1.0e-3f) / tm;
            const float a1 = (-1.0e-3f) / ts;
            const float e0 = (float)exp((double)a0);
            const float e1 = (float)exp((double)a1);
            const float diff     = ts - tm;
            const float mul_term = (diff == 0.0f) ? 0.0f : (ts * tm) / diff;
            p00[h][e] = e0;
            p11[h][e] = e1;
            p01[h][e] = mul_term * (e1 - e0);
            itau[k]   = 1.0 / (double)ts;
            trf[h][e] = tau_ref_p[n0 + k];
            thv[h][e] = thresh_p[n0 + k];
            rsv[h][e] = reset_p[n0 + k];
            v[h][e]   = v_init[n0 + k];
            c[h][e]   = c_init[n0 + k];
            tmr[h][e] = 0.0f;
        }
    }

    u64 refball = 0;   // wave-uniform: lanes whose neurons have nonzero timers

    const float4* pS = (const float4*)SPa;
    const float4* pX = (const float4*)Da;
    const float4* pY = (const float4*)DVa;

    __syncthreads();

    float4 sA = pS[tid],        xA = pX[tid],        yA = pY[tid];
    float4 sB = pS[1024 + tid], xB = pX[1024 + tid], yB = pY[1024 + tid];
    pS += 2048; pX += 2048; pY += 2048;

    auto do_step = [&](int t, float4& S, float4& X, float4& Y) {
#pragma clang fp contract(off)
        const int p = t % 3;
        // capture step-t drive BEFORE the prefetch overwrites the buffers
        const float4 Sc = S, Xc = X, Yc = Y;
        const f32x2 sp0 = mk2(Sc.x, Sc.y), sp1 = mk2(Sc.z, Sc.w);

        f32x2 vu[NPH];
        vu[0] = (v[0] * p00[0] + c[0] * p01[0]) + sp0;
        vu[1] = (v[1] * p00[1] + c[1] * p01[1]) + sp1;
        c[0] = c[0] * p11[0];
        c[1] = c[1] * p11[1];

        // conservative spike gate: vu>=th ⟹ (vu-th)>=0 (rounding is monotone)
        const float g = fmaxf(fmaxf(vu[0][0] - thv[0][0], vu[0][1] - thv[0][1]),
                              fmaxf(vu[1][0] - thv[1][0], vu[1][1] - thv[1][1]));
        f32x2 sv[NPH] = { mk2(0.f, 0.f), mk2(0.f, 0.f) };

        if (__ballot(g >= 0.0f) | refball) {
            // slow path: exact per-neuron select logic (identical to R3)
            u32 nib = 0;
#pragma unroll
            for (int h = 0; h < NPH; ++h) {
#pragma unroll
                for (int e = 0; e < 2; ++e) {
                    const bool  isref = (tmr[h][e] != 0.0f);
                    const float x     = isref ? rsv[h][e] : vu[h][e];
                    const bool  sp    = (x >= thv[h][e]);
                    v[h][e]  = sp ? rsv[h][e] : x;
                    sv[h][e] = sp ? 1.0f : 0.0f;
                    const float tt = sp ? trf[h][e] : tmr[h][e];
                    tmr[h][e] = isref ? (tt - 1.0e-3f) : tt;
                    nib |= sp ? (1u << (2 * h + e)) : 0u;
                }
            }
            if (nib)
                atomicOr(((u32*)&mask64[0][0]) + p * 128 + (tid >> 3),
                         nib << ((tid & 7) * 4));
            const int anyr = (tmr[0][0] != 0.0f) | (tmr[0][1] != 0.0f) |
                             (tmr[1][0] != 0.0f) | (tmr[1][1] != 0.0f);
            refball = __ballot(anyr);
        } else {
            v[0] = vu[0];
            v[1] = vu[1];
        }

        // prefetch t+2 (uniform); loads stay in flight across the barrier
        if (t + 2 < T_STEPS) {
            S = pS[tid]; X = pX[tid]; Y = pY[tid];
            pS += 1024; pX += 1024; pY += 1024;
        }

        asm volatile("s_waitcnt lgkmcnt(0)" ::: "memory");
        __builtin_amdgcn_s_barrier();
        __builtin_amdgcn_sched_barrier(0);

        const u64 mym  = mask64[p][lane];
        u64       summ = __ballot(mym != 0ull);
        if (tid < 64) mask64[(t + 2) % 3][tid] = 0ull;

        if (summ == 0ull) {
            // no spikes network-wide: c += D/ts (precomputed, == (0+D)/ts bitwise)
            c[0] += mk2(Yc.x, Yc.y);
            c[1] += mk2(Yc.z, Yc.w);
        } else {
            // ---- 6-deep pipelined gather; chunk masks via readlane --------
            f32x2 ws0 = mk2(0.f, 0.f), ws1 = mk2(0.f, 0.f);
            const u32 mlo = (u32)(mym & 0xffffffffull);
            const u32 mhi = (u32)(mym >> 32);
            u64 rem = summ;
            int b = (int)__builtin_ctzll(rem); rem &= rem - 1;
            u64 bits = ((u64)(u32)__builtin_amdgcn_readlane((int)mhi, b) << 32)
                     |  (u64)(u32)__builtin_amdgcn_readlane((int)mlo, b);

            // NEXTJ: declare jv; -1 when exhausted.  Scalar-pipe only.
#define NEXTJ(jv)                                                           \
            int jv = -1;                                                    \
            for (;;) {                                                      \
                if (bits) {                                                 \
                    jv = (b << 6) + (int)__builtin_ctzll(bits);             \
                    bits &= bits - 1;                                       \
                    break;                                                  \
                }                                                           \
                if (!rem) break;                                            \
                b = (int)__builtin_ctzll(rem); rem &= rem - 1;              \
                bits = ((u64)(u32)__builtin_amdgcn_readlane((int)mhi, b) << 32) \
                     |  (u64)(u32)__builtin_amdgcn_readlane((int)mlo, b);   \
            }

            NEXTJ(j0)                           // always valid (summ != 0)
            float4 Q0 = *(const float4*)(WT + (size_t)j0 * N_NEU + n0);
            NEXTJ(j1)
            const float w1 = (j1 >= 0) ? 1.0f : 0.0f;
            float4 Q1 = *(const float4*)(WT + (size_t)(j1 >= 0 ? j1 : j0) * N_NEU + n0);
            NEXTJ(j2)
            const float w2 = (j2 >= 0) ? 1.0f : 0.0f;
            float4 Q2 = *(const float4*)(WT + (size_t)(j2 >= 0 ? j2 : j0) * N_NEU + n0);
            NEXTJ(j3)
            const float w3 = (j3 >= 0) ? 1.0f : 0.0f;
            float4 Q3 = *(const float4*)(WT + (size_t)(j3 >= 0 ? j3 : j0) * N_NEU + n0);
            NEXTJ(j4)
            const float w4 = (j4 >= 0) ? 1.0f : 0.0f;
            float4 Q4 = *(const float4*)(WT + (size_t)(j4 >= 0 ? j4 : j0) * N_NEU + n0);
            NEXTJ(j5)
            const float w5 = (j5 >= 0) ? 1.0f : 0.0f;
            float4 Q5 = *(const float4*)(WT + (size_t)(j5 >= 0 ? j5 : j0) * N_NEU + n0);

            // steady state: 6 loads in flight; accumulate oldest (ascending)
            for (;;) {
                NEXTJ(jn)
                if (jn < 0) break;
                const float4 Qn = *(const float4*)(WT + (size_t)jn * N_NEU + n0);
                ws0 += mk2(Q0.x, Q0.y);         // vmcnt(5): Q0 ready
                ws1 += mk2(Q0.z, Q0.w);
                Q0 = Q1; Q1 = Q2; Q2 = Q3; Q3 = Q4; Q4 = Q5; Q5 = Qn;
            }
            // drain, ascending order; single chain; fmaf identity for pads
            ws0 += mk2(Q0.x, Q0.y);
            ws1 += mk2(Q0.z, Q0.w);
            ws0[0] = fmaf(w1, Q1.x, ws0[0]);   ws0[1] = fmaf(w1, Q1.y, ws0[1]);
            ws1[0] = fmaf(w1, Q1.z, ws1[0]);   ws1[1] = fmaf(w1, Q1.w, ws1[1]);
            ws0[0] = fmaf(w2, Q2.x, ws0[0]);   ws0[1] = fmaf(w2, Q2.y, ws0[1]);
            ws1[0] = fmaf(w2, Q2.z, ws1[0]);   ws1[1] = fmaf(w2, Q2.w, ws1[1]);
            ws0[0] = fmaf(w3, Q3.x, ws0[0]);   ws0[1] = fmaf(w3, Q3.y, ws0[1]);
            ws1[0] = fmaf(w3, Q3.z, ws1[0]);   ws1[1] = fmaf(w3, Q3.w, ws1[1]);
            ws0[0] = fmaf(w4, Q4.x, ws0[0]);   ws0[1] = fmaf(w4, Q4.y, ws0[1]);
            ws1[0] = fmaf(w4, Q4.z, ws1[0]);   ws1[1] = fmaf(w4, Q4.w, ws1[1]);
            ws0[0] = fmaf(w5, Q5.x, ws0[0]);   ws0[1] = fmaf(w5, Q5.y, ws0[1]);
            ws1[0] = fmaf(w5, Q5.z, ws1[0]);   ws1[1] = fmaf(w5, Q5.w, ws1[1]);
#undef NEXTJ

            const f32x2 acc0 = ws0 + mk2(Xc.x, Xc.y);
            const f32x2 acc1 = ws1 + mk2(Xc.z, Xc.w);
            c[0][0] += (float)((double)acc0[0] * itau[0]);
            c[0][1] += (float)((double)acc0[1] * itau[1]);
            c[1][0] += (float)((double)acc1[0] * itau[2]);
            c[1][1] += (float)((double)acc1[1] * itau[3]);
        }

        if (t % NB == bid) {
            float4* oV = (float4*)(outV + (size_t)t * N_NEU + n0);
            float4* oC = (float4*)(outC + (size_t)t * N_NEU + n0);
            float4* oS = (float4*)(outS + (size_t)t * N_NEU + n0);
            *oV = make_float4(v[0][0], v[0][1], v[1][0], v[1][1]);
            *oC = make_float4(c[0][0], c[0][1], c[1][0], c[1][1]);
            *oS = make_float4(sv[0][0], sv[0][1], sv[1][0], sv[1][1]);
        }
    };

    for (int t = 0; t < T_STEPS; t += 2) {
        do_step(t,     sA, xA, yA);
        do_step(t + 1, sB, xB, yB);
    }
}

// ---------------------------------------------------------------------------
// TIER B: the validated R3 kernel (fallback when ws is too small).
// ---------------------------------------------------------------------------
template <bool USE_WT>
__global__ __launch_bounds__(NTHREADS, 1)
void lif_kernel(const float* __restrict__ v_init,
                const float* __restrict__ c_init,
                const float* __restrict__ stim,
                const float* __restrict__ ext,
                const float* __restrict__ W,
                const float* __restrict__ WT,
                const float* __restrict__ j_ext,
                const float* __restrict__ tau_m_p,
                const float* __restrict__ tau_s_p,
                const float* __restrict__ tau_ref_p,
                const float* __restrict__ thresh_p,
                const float* __restrict__ reset_p,
                float* __restrict__ outV,
                float* __restrict__ outC,
                float* __restrict__ outS)
{
#pragma clang fp contract(off)
    const int tid  = threadIdx.x;
    const int bid  = blockIdx.x;
    const int n0   = tid * NPT;
    const int lane = tid & 63;

    __shared__ u64 mask64[3][64];
    if (tid < 192) ((u64*)mask64)[tid] = 0ull;

    f32x2 p00[NPH], p01[NPH], p02[NPH], p11[NPH], trf[NPH], thv[NPH], rsv[NPH];
    f32x2 v[NPH], c[NPH], tmr[NPH];
    double itau[NPT];

#pragma unroll
    for (int h = 0; h < NPH; ++h) {
#pragma unroll
        for (int e = 0; e < 2; ++e) {
            const int k = 2 * h + e;
            const float tm = tau_m_p[n0 + k], ts = tau_s_p[n0 + k];
            const float a0 = (-1.0e-3f) / tm;
            const float a1 = (-1.0e-3f) / ts;
            const float e0 = (float)exp((double)a0);
            const float e1 = (float)exp((double)a1);
            const float diff     = ts - tm;
            const float mul_term = (diff == 0.0f) ? 0.0f : (ts * tm) / diff;
            p00[h][e] = e0;
            p11[h][e] = e1;
            p01[h][e] = mul_term * (e1 - e0);
            p02[h][e] = tm * (1.0f - e0);
            itau[k]   = 1.0 / (double)ts;
            trf[h][e] = tau_ref_p[n0 + k];
            thv[h][e] = thresh_p[n0 + k];
            rsv[h][e] = reset_p[n0 + k];
            v[h][e]   = v_init[n0 + k];
            c[h][e]   = c_init[n0 + k];
            tmr[h][e] = 0.0f;
        }
    }

    const float jw0 = j_ext[0], jw1 = j_ext[1];
    const f32x2 jv0 = mk2(jw0, jw0), jv1 = mk2(jw1, jw1);

    const float4* stim4 = (const float4*)stim + tid;
    const float4* e04   = (const float4*)ext + tid;
    const float4* e14   = (const float4*)(ext + N_NEU) + tid;

    __syncthreads();

    float4 sA = stim4[0],    xA = e04[0],    yA = e14[0];
    float4 sB = stim4[1024], xB = e04[2048], yB = e14[2048];

    auto do_step = [&](int t, float4& S, float4& X, float4& Y) {
#pragma clang fp contract(off)
        const int p = t % 3;
        f32x2 st[NPH] = { mk2(S.x, S.y), mk2(S.z, S.w) };
        f32x2 ex[NPH] = { mk2(X.x, X.y), mk2(X.z, X.w) };
        f32x2 ey[NPH] = { mk2(Y.x, Y.y), mk2(Y.z, Y.w) };

        f32x2 sv[NPH], jx[NPH];
        u32 nib = 0;
#pragma unroll
        for (int h = 0; h < NPH; ++h) {
            f32x2 vu = (v[h] * p00[h] + c[h] * p01[h]) + st[h] * p02[h];
            c[h] = c[h] * p11[h];
            jx[h] = jv0 * ex[h] + jv1 * ey[h];
#pragma unroll
            for (int e = 0; e < 2; ++e) {
                const bool  isref = (tmr[h][e] != 0.0f);
                const float x     = isref ? rsv[h][e] : vu[e];
                const bool  sp    = (x >= thv[h][e]);
                v[h][e]  = sp ? rsv[h][e] : x;
                sv[h][e] = sp ? 1.0f : 0.0f;
                const float tt = sp ? trf[h][e] : tmr[h][e];
                tmr[h][e] = isref ? (tt - 1.0e-3f) : tt;
                nib |= sp ? (1u << (2 * h + e)) : 0u;
            }
        }
        if (nib)
            atomicOr(((u32*)&mask64[0][0]) + p * 128 + (tid >> 3),
                     nib << ((tid & 7) * 4));

        if (t + 2 < T_STEPS) {
            S = stim4[(size_t)(t + 2) * 1024];
            X = e04[(size_t)(t + 2) * 2048];
            Y = e14[(size_t)(t + 2) * 2048];
        }

        asm volatile("s_waitcnt lgkmcnt(0)" ::: "memory");
        __builtin_amdgcn_s_barrier();
        __builtin_amdgcn_sched_barrier(0);

        const u64 mym  = mask64[p][lane];
        u64       summ = __ballot(mym != 0ull);
        if (tid < 64) mask64[(t + 2) % 3][tid] = 0ull;

        f32x2 ws[NPH] = { mk2(0.f, 0.f), mk2(0.f, 0.f) };
        while (summ) {
            const int b = __builtin_ctzll(summ);
            summ &= summ - 1;
            u64 bits = __shfl(mym, b);
            while (bits) {
                const int q = __builtin_ctzll(bits);
                bits &= bits - 1;
                const int j = b * 64 + q;
                if (USE_WT) {
                    const float4 col = *(const float4*)(WT + (size_t)j * N_NEU + n0);
                    ws[0] += mk2(col.x, col.y);
                    ws[1] += mk2(col.z, col.w);
                } else {
#pragma unroll
                    for (int h = 0; h < NPH; ++h) {
                        ws[h][0] += W[(size_t)(n0 + 2 * h)     * N_NEU + j];
                        ws[h][1] += W[(size_t)(n0 + 2 * h + 1) * N_NEU + j];
                    }
                }
            }
        }

#pragma unroll
        for (int h = 0; h < NPH; ++h) {
            const f32x2 acc = ws[h] + jx[h];
            c[h][0] = c[h][0] + (float)((double)acc[0] * itau[2 * h]);
            c[h][1] = c[h][1] + (float)((double)acc[1] * itau[2 * h + 1]);
        }

        if (t % NB == bid) {
            float4* oV = (float4*)(outV + (size_t)t * N_NEU + n0);
            float4* oC = (float4*)(outC + (size_t)t * N_NEU + n0);
            float4* oS = (float4*)(outS + (size_t)t * N_NEU + n0);
            *oV = make_float4(v[0][0], v[0][1], v[1][0], v[1][1]);
            *oC = make_float4(c[0][0], c[0][1], c[1][0], c[1][1]);
            *oS = make_float4(sv[0][0], sv[0][1], sv[1][0], sv[1][1]);
        }
    };

    for (int t = 0; t < T_STEPS; t += 2) {
        do_step(t,     sA, xA, yA);
        do_step(t + 1, sB, xB, yB);
    }
}

// ---------------------------------------------------------------------------
extern "C" void kernel_launch(void* const* d_in, const int* in_sizes, int n_in,
                              void* d_out, int out_size, void* d_ws, size_t ws_size,
                              hipStream_t stream)
{
    const float* v0     = (const float*)d_in[0];
    const float* c0     = (const float*)d_in[1];
    const float* stim   = (const float*)d_in[2];
    const float* ext    = (const float*)d_in[3];
    const float* W      = (const float*)d_in[4];
    const float* jext   = (const float*)d_in[5];
    const float* taum   = (const float*)d_in[6];
    const float* taus   = (const float*)d_in[7];
    const float* tauref = (const float*)d_in[8];
    const float* thr    = (const float*)d_in[9];
    const float* rst    = (const float*)d_in[10];

    float* outV = (float*)d_out;
    float* outC = outV + (size_t)T_STEPS * N_NEU;
    float* outS = outC + (size_t)T_STEPS * N_NEU;

    const size_t WT_B   = (size_t)N_NEU * N_NEU * sizeof(float);       // 64 MiB
    const size_t ARR_B  = (size_t)T_STEPS * N_NEU * sizeof(float);     // 31.25 MiB
    const size_t NEED_A = WT_B + 3 * ARR_B;

    if (ws_size >= NEED_A) {
        float* WT  = (float*)d_ws;
        float* SPa = (float*)((char*)d_ws + WT_B);
        float* Da  = SPa + (size_t)T_STEPS * N_NEU;
        float* DVa = Da  + (size_t)T_STEPS * N_NEU;
        transpose_kernel<<<dim3(128, 128), dim3(32, 8), 0, stream>>>(W, WT);
        prep_kernel<<<8000, 256, 0, stream>>>(stim, ext, jext, taum, taus,
                                              SPa, Da, DVa);
        lifA_kernel<<<NB, NTHREADS, 0, stream>>>(
            v0, c0, SPa, Da, DVa, WT, taum, taus, tauref, thr, rst,
            outV, outC, outS);
    } else if (ws_size >= WT_B) {
        float* WT = (float*)d_ws;
        transpose_kernel<<<dim3(128, 128), dim3(32, 8), 0, stream>>>(W, WT);
        lif_kernel<true><<<NB, NTHREADS, 0, stream>>>(
            v0, c0, stim, ext, W, WT, jext, taum, taus, tauref, thr, rst,
            outV, outC, outS);
    } else {
        lif_kernel<false><<<NB, NTHREADS, 0, stream>>>(
            v0, c0, stim, ext, W, (const float*)nullptr, jext, taum, taus,
            tauref, thr, rst, outV, outC, outS);
    }
}

// Round 7
// 1523.131 us; speedup vs baseline: 2.1999x; 2.1999x over previous
//
#include <hip/hip_runtime.h>
#include <math.h>

#define N_NEU    4096
#define T_STEPS  2000
#define NTHREADS 1024
#define NPT      4      // neurons per thread
#define NPH      2      // f32x2 pairs per thread
#define NB       16     // replicated blocks; block b writes steps t%NB==b

typedef unsigned int       u32;
typedef unsigned long long u64;
typedef float f32x2 __attribute__((ext_vector_type(2)));

static __device__ __forceinline__ f32x2 mk2(float a, float b) {
    f32x2 r; r[0] = a; r[1] = b; return r;
}

// ---------------------------------------------------------------------------
__global__ void transpose_kernel(const float* __restrict__ W, float* __restrict__ WT)
{
    __shared__ float tile[32][33];
    const int bx = blockIdx.x * 32, by = blockIdx.y * 32;
    const int tx = threadIdx.x, ty = threadIdx.y;
#pragma unroll
    for (int k = 0; k < 32; k += 8)
        tile[ty + k][tx] = W[(size_t)(by + ty + k) * N_NEU + (bx + tx)];
    __syncthreads();
#pragma unroll
    for (int k = 0; k < 32; k += 8)
        WT[(size_t)(bx + ty + k) * N_NEU + (by + tx)] = tile[tx][ty + k];
}

// ---------------------------------------------------------------------------
// Precompute per-step drive terms with ops BIT-IDENTICAL to the in-loop forms:
//   SP[t][n] = stim[t][n] * p02[n]              (f32 mul)
//   D [t][n] = jw0*ext0 + jw1*ext1              (f32 mul,mul,add)
//   DV[t][n] = (f32)((f64)D * (1.0/(f64)ts))    (== no-spike c increment)
// ---------------------------------------------------------------------------
__global__ void prep_kernel(const float* __restrict__ stim,
                            const float* __restrict__ ext,
                            const float* __restrict__ jext,
                            const float* __restrict__ taum,
                            const float* __restrict__ taus,
                            float* __restrict__ SPa,
                            float* __restrict__ Da,
                            float* __restrict__ DVa)
{
#pragma clang fp contract(off)
    const int i = blockIdx.x * 256 + threadIdx.x;   // float4 index, 2048000 total
    const int t = i >> 10, k = i & 1023;
    const float4 s4  = ((const float4*)stim)[i];
    const float4 a4  = ((const float4*)ext)[(size_t)t * 2048 + k];
    const float4 b4  = ((const float4*)ext)[(size_t)t * 2048 + 1024 + k];
    const float4 tm4 = ((const float4*)taum)[k];
    const float4 ts4 = ((const float4*)taus)[k];
    const float jw0 = jext[0], jw1 = jext[1];
    float4 sp, dd, dv;
#define PREP1(F)                                                            \
    {                                                                       \
        const float tm = tm4.F;                                             \
        const float e0 = (float)exp((double)((-1.0e-3f) / tm));             \
        const float p02 = tm * (1.0f - e0);                                 \
        sp.F = s4.F * p02;                                                  \
        dd.F = jw0 * a4.F + jw1 * b4.F;                                     \
        dv.F = (float)((double)dd.F * (1.0 / (double)ts4.F));               \
    }
    PREP1(x) PREP1(y) PREP1(z) PREP1(w)
#undef PREP1
    ((float4*)SPa)[i] = sp;
    ((float4*)Da)[i]  = dd;
    ((float4*)DVa)[i] = dv;
}

// ---------------------------------------------------------------------------
// TIER A: replicated LIF with precomputed drives + wave-uniform fast path.
// R(this): revert of the R6 6-stage rotation (2.2x regression: wide named
// rotation -> 20+ v_mov/column + branchy weighted prologue).  Exact R5
// structure (validated 1533us) with the minimal rotation extended 3 -> 4
// stages only: same early-exit prologue style, same scalar-pipe NEXTJ
// extraction, 12 movs/iter.  Accumulation remains ONE chain in strict
// ascending neuron order -> bitwise identical to the serial loop.
// Pre-commit: if this is within noise of R5, the replicated design is at
// its per-CU L2-return-BW floor (~224KB/step / ~128 B/cyc ≈ 1750 cyc/step).
// ---------------------------------------------------------------------------
__global__ __launch_bounds__(NTHREADS, 1)
void lifA_kernel(const float* __restrict__ v_init,
                 const float* __restrict__ c_init,
                 const float* __restrict__ SPa,
                 const float* __restrict__ Da,
                 const float* __restrict__ DVa,
                 const float* __restrict__ WT,
                 const float* __restrict__ tau_m_p,
                 const float* __restrict__ tau_s_p,
                 const float* __restrict__ tau_ref_p,
                 const float* __restrict__ thresh_p,
                 const float* __restrict__ reset_p,
                 float* __restrict__ outV,
                 float* __restrict__ outC,
                 float* __restrict__ outS)
{
#pragma clang fp contract(off)
    const int tid  = threadIdx.x;
    const int bid  = blockIdx.x;
    const int n0   = tid * NPT;
    const int lane = tid & 63;

    __shared__ u64 mask64[3][64];
    if (tid < 192) ((u64*)mask64)[tid] = 0ull;

    f32x2 p00[NPH], p01[NPH], p11[NPH], trf[NPH], thv[NPH], rsv[NPH];
    f32x2 v[NPH], c[NPH], tmr[NPH];
    double itau[NPT];

#pragma unroll
    for (int h = 0; h < NPH; ++h) {
#pragma unroll
        for (int e = 0; e < 2; ++e) {
            const int k = 2 * h + e;
            const float tm = tau_m_p[n0 + k], ts = tau_s_p[n0 + k];
            const float a0 = (-1.0e-3f) / tm;
            const float a1 = (-1.0e-3f) / ts;
            const float e0 = (float)exp((double)a0);
            const float e1 = (float)exp((double)a1);
            const float diff     = ts - tm;
            const float mul_term = (diff == 0.0f) ? 0.0f : (ts * tm) / diff;
            p00[h][e] = e0;
            p11[h][e] = e1;
            p01[h][e] = mul_term * (e1 - e0);
            itau[k]   = 1.0 / (double)ts;
            trf[h][e] = tau_ref_p[n0 + k];
            thv[h][e] = thresh_p[n0 + k];
            rsv[h][e] = reset_p[n0 + k];
            v[h][e]   = v_init[n0 + k];
            c[h][e]   = c_init[n0 + k];
            tmr[h][e] = 0.0f;
        }
    }

    u64 refball = 0;   // wave-uniform: lanes whose neurons have nonzero timers

    const float4* pS = (const float4*)SPa;
    const float4* pX = (const float4*)Da;
    const float4* pY = (const float4*)DVa;

    __syncthreads();

    float4 sA = pS[tid],        xA = pX[tid],        yA = pY[tid];
    float4 sB = pS[1024 + tid], xB = pX[1024 + tid], yB = pY[1024 + tid];
    pS += 2048; pX += 2048; pY += 2048;

    auto do_step = [&](int t, float4& S, float4& X, float4& Y) {
#pragma clang fp contract(off)
        const int p = t % 3;
        // capture step-t drive BEFORE the prefetch overwrites the buffers
        const float4 Sc = S, Xc = X, Yc = Y;
        const f32x2 sp0 = mk2(Sc.x, Sc.y), sp1 = mk2(Sc.z, Sc.w);

        f32x2 vu[NPH];
        vu[0] = (v[0] * p00[0] + c[0] * p01[0]) + sp0;
        vu[1] = (v[1] * p00[1] + c[1] * p01[1]) + sp1;
        c[0] = c[0] * p11[0];
        c[1] = c[1] * p11[1];

        // conservative spike gate: vu>=th ⟹ (vu-th)>=0 (rounding is monotone)
        const float g = fmaxf(fmaxf(vu[0][0] - thv[0][0], vu[0][1] - thv[0][1]),
                              fmaxf(vu[1][0] - thv[1][0], vu[1][1] - thv[1][1]));
        f32x2 sv[NPH] = { mk2(0.f, 0.f), mk2(0.f, 0.f) };

        if (__ballot(g >= 0.0f) | refball) {
            // slow path: exact per-neuron select logic (identical to R3)
            u32 nib = 0;
#pragma unroll
            for (int h = 0; h < NPH; ++h) {
#pragma unroll
                for (int e = 0; e < 2; ++e) {
                    const bool  isref = (tmr[h][e] != 0.0f);
                    const float x     = isref ? rsv[h][e] : vu[h][e];
                    const bool  sp    = (x >= thv[h][e]);
                    v[h][e]  = sp ? rsv[h][e] : x;
                    sv[h][e] = sp ? 1.0f : 0.0f;
                    const float tt = sp ? trf[h][e] : tmr[h][e];
                    tmr[h][e] = isref ? (tt - 1.0e-3f) : tt;
                    nib |= sp ? (1u << (2 * h + e)) : 0u;
                }
            }
            if (nib)
                atomicOr(((u32*)&mask64[0][0]) + p * 128 + (tid >> 3),
                         nib << ((tid & 7) * 4));
            const int anyr = (tmr[0][0] != 0.0f) | (tmr[0][1] != 0.0f) |
                             (tmr[1][0] != 0.0f) | (tmr[1][1] != 0.0f);
            refball = __ballot(anyr);
        } else {
            v[0] = vu[0];
            v[1] = vu[1];
        }

        // prefetch t+2 (uniform); loads stay in flight across the barrier
        if (t + 2 < T_STEPS) {
            S = pS[tid]; X = pX[tid]; Y = pY[tid];
            pS += 1024; pX += 1024; pY += 1024;
        }

        asm volatile("s_waitcnt lgkmcnt(0)" ::: "memory");
        __builtin_amdgcn_s_barrier();
        __builtin_amdgcn_sched_barrier(0);

        const u64 mym  = mask64[p][lane];
        u64       summ = __ballot(mym != 0ull);
        if (tid < 64) mask64[(t + 2) % 3][tid] = 0ull;

        if (summ == 0ull) {
            // no spikes network-wide: c += D/ts (precomputed, == (0+D)/ts bitwise)
            c[0] += mk2(Yc.x, Yc.y);
            c[1] += mk2(Yc.z, Yc.w);
        } else {
            // ---- 4-deep pipelined gather; chunk masks via readlane --------
            f32x2 ws0 = mk2(0.f, 0.f), ws1 = mk2(0.f, 0.f);
            const u32 mlo = (u32)(mym & 0xffffffffull);
            const u32 mhi = (u32)(mym >> 32);
            u64 rem = summ;
            int b = (int)__builtin_ctzll(rem); rem &= rem - 1;
            u64 bits = ((u64)(u32)__builtin_amdgcn_readlane((int)mhi, b) << 32)
                     |  (u64)(u32)__builtin_amdgcn_readlane((int)mlo, b);

            // NEXTJ: declare jv; -1 when exhausted.  Scalar-pipe only.
#define NEXTJ(jv)                                                           \
            int jv = -1;                                                    \
            for (;;) {                                                      \
                if (bits) {                                                 \
                    jv = (b << 6) + (int)__builtin_ctzll(bits);             \
                    bits &= bits - 1;                                       \
                    break;                                                  \
                }                                                           \
                if (!rem) break;                                            \
                b = (int)__builtin_ctzll(rem); rem &= rem - 1;              \
                bits = ((u64)(u32)__builtin_amdgcn_readlane((int)mhi, b) << 32) \
                     |  (u64)(u32)__builtin_amdgcn_readlane((int)mlo, b);   \
            }

            NEXTJ(j0)                           // always valid (summ != 0)
            float4 Qa = *(const float4*)(WT + (size_t)j0 * N_NEU + n0);
            NEXTJ(j1)
            if (j1 < 0) {
                ws0 += mk2(Qa.x, Qa.y);
                ws1 += mk2(Qa.z, Qa.w);
            } else {
                float4 Qb = *(const float4*)(WT + (size_t)j1 * N_NEU + n0);
                NEXTJ(j2)
                if (j2 < 0) {
                    ws0 += mk2(Qa.x, Qa.y);     // drain, ascending order
                    ws1 += mk2(Qa.z, Qa.w);
                    ws0 += mk2(Qb.x, Qb.y);
                    ws1 += mk2(Qb.z, Qb.w);
                } else {
                    float4 Qc = *(const float4*)(WT + (size_t)j2 * N_NEU + n0);
                    for (;;) {
                        NEXTJ(jn)
                        if (jn < 0) break;
                        const float4 Qd = *(const float4*)(WT + (size_t)jn * N_NEU + n0);
                        // vmcnt(3): Qa ready; Qb,Qc,Qd in flight
                        ws0 += mk2(Qa.x, Qa.y);
                        ws1 += mk2(Qa.z, Qa.w);
                        Qa = Qb; Qb = Qc; Qc = Qd;
                    }
                    ws0 += mk2(Qa.x, Qa.y);     // drain, ascending order
                    ws1 += mk2(Qa.z, Qa.w);
                    ws0 += mk2(Qb.x, Qb.y);
                    ws1 += mk2(Qb.z, Qb.w);
                    ws0 += mk2(Qc.x, Qc.y);
                    ws1 += mk2(Qc.z, Qc.w);
                }
            }
#undef NEXTJ

            const f32x2 acc0 = ws0 + mk2(Xc.x, Xc.y);
            const f32x2 acc1 = ws1 + mk2(Xc.z, Xc.w);
            c[0][0] += (float)((double)acc0[0] * itau[0]);
            c[0][1] += (float)((double)acc0[1] * itau[1]);
            c[1][0] += (float)((double)acc1[0] * itau[2]);
            c[1][1] += (float)((double)acc1[1] * itau[3]);
        }

        if (t % NB == bid) {
            float4* oV = (float4*)(outV + (size_t)t * N_NEU + n0);
            float4* oC = (float4*)(outC + (size_t)t * N_NEU + n0);
            float4* oS = (float4*)(outS + (size_t)t * N_NEU + n0);
            *oV = make_float4(v[0][0], v[0][1], v[1][0], v[1][1]);
            *oC = make_float4(c[0][0], c[0][1], c[1][0], c[1][1]);
            *oS = make_float4(sv[0][0], sv[0][1], sv[1][0], sv[1][1]);
        }
    };

    for (int t = 0; t < T_STEPS; t += 2) {
        do_step(t,     sA, xA, yA);
        do_step(t + 1, sB, xB, yB);
    }
}

// ---------------------------------------------------------------------------
// TIER B: the validated R3 kernel (fallback when ws is too small).
// ---------------------------------------------------------------------------
template <bool USE_WT>
__global__ __launch_bounds__(NTHREADS, 1)
void lif_kernel(const float* __restrict__ v_init,
                const float* __restrict__ c_init,
                const float* __restrict__ stim,
                const float* __restrict__ ext,
                const float* __restrict__ W,
                const float* __restrict__ WT,
                const float* __restrict__ j_ext,
                const float* __restrict__ tau_m_p,
                const float* __restrict__ tau_s_p,
                const float* __restrict__ tau_ref_p,
                const float* __restrict__ thresh_p,
                const float* __restrict__ reset_p,
                float* __restrict__ outV,
                float* __restrict__ outC,
                float* __restrict__ outS)
{
#pragma clang fp contract(off)
    const int tid  = threadIdx.x;
    const int bid  = blockIdx.x;
    const int n0   = tid * NPT;
    const int lane = tid & 63;

    __shared__ u64 mask64[3][64];
    if (tid < 192) ((u64*)mask64)[tid] = 0ull;

    f32x2 p00[NPH], p01[NPH], p02[NPH], p11[NPH], trf[NPH], thv[NPH], rsv[NPH];
    f32x2 v[NPH], c[NPH], tmr[NPH];
    double itau[NPT];

#pragma unroll
    for (int h = 0; h < NPH; ++h) {
#pragma unroll
        for (int e = 0; e < 2; ++e) {
            const int k = 2 * h + e;
            const float tm = tau_m_p[n0 + k], ts = tau_s_p[n0 + k];
            const float a0 = (-1.0e-3f) / tm;
            const float a1 = (-1.0e-3f) / ts;
            const float e0 = (float)exp((double)a0);
            const float e1 = (float)exp((double)a1);
            const float diff     = ts - tm;
            const float mul_term = (diff == 0.0f) ? 0.0f : (ts * tm) / diff;
            p00[h][e] = e0;
            p11[h][e] = e1;
            p01[h][e] = mul_term * (e1 - e0);
            p02[h][e] = tm * (1.0f - e0);
            itau[k]   = 1.0 / (double)ts;
            trf[h][e] = tau_ref_p[n0 + k];
            thv[h][e] = thresh_p[n0 + k];
            rsv[h][e] = reset_p[n0 + k];
            v[h][e]   = v_init[n0 + k];
            c[h][e]   = c_init[n0 + k];
            tmr[h][e] = 0.0f;
        }
    }

    const float jw0 = j_ext[0], jw1 = j_ext[1];
    const f32x2 jv0 = mk2(jw0, jw0), jv1 = mk2(jw1, jw1);

    const float4* stim4 = (const float4*)stim + tid;
    const float4* e04   = (const float4*)ext + tid;
    const float4* e14   = (const float4*)(ext + N_NEU) + tid;

    __syncthreads();

    float4 sA = stim4[0],    xA = e04[0],    yA = e14[0];
    float4 sB = stim4[1024], xB = e04[2048], yB = e14[2048];

    auto do_step = [&](int t, float4& S, float4& X, float4& Y) {
#pragma clang fp contract(off)
        const int p = t % 3;
        f32x2 st[NPH] = { mk2(S.x, S.y), mk2(S.z, S.w) };
        f32x2 ex[NPH] = { mk2(X.x, X.y), mk2(X.z, X.w) };
        f32x2 ey[NPH] = { mk2(Y.x, Y.y), mk2(Y.z, Y.w) };

        f32x2 sv[NPH], jx[NPH];
        u32 nib = 0;
#pragma unroll
        for (int h = 0; h < NPH; ++h) {
            f32x2 vu = (v[h] * p00[h] + c[h] * p01[h]) + st[h] * p02[h];
            c[h] = c[h] * p11[h];
            jx[h] = jv0 * ex[h] + jv1 * ey[h];
#pragma unroll
            for (int e = 0; e < 2; ++e) {
                const bool  isref = (tmr[h][e] != 0.0f);
                const float x     = isref ? rsv[h][e] : vu[e];
                const bool  sp    = (x >= thv[h][e]);
                v[h][e]  = sp ? rsv[h][e] : x;
                sv[h][e] = sp ? 1.0f : 0.0f;
                const float tt = sp ? trf[h][e] : tmr[h][e];
                tmr[h][e] = isref ? (tt - 1.0e-3f) : tt;
                nib |= sp ? (1u << (2 * h + e)) : 0u;
            }
        }
        if (nib)
            atomicOr(((u32*)&mask64[0][0]) + p * 128 + (tid >> 3),
                     nib << ((tid & 7) * 4));

        if (t + 2 < T_STEPS) {
            S = stim4[(size_t)(t + 2) * 1024];
            X = e04[(size_t)(t + 2) * 2048];
            Y = e14[(size_t)(t + 2) * 2048];
        }

        asm volatile("s_waitcnt lgkmcnt(0)" ::: "memory");
        __builtin_amdgcn_s_barrier();
        __builtin_amdgcn_sched_barrier(0);

        const u64 mym  = mask64[p][lane];
        u64       summ = __ballot(mym != 0ull);
        if (tid < 64) mask64[(t + 2) % 3][tid] = 0ull;

        f32x2 ws[NPH] = { mk2(0.f, 0.f), mk2(0.f, 0.f) };
        while (summ) {
            const int b = __builtin_ctzll(summ);
            summ &= summ - 1;
            u64 bits = __shfl(mym, b);
            while (bits) {
                const int q = __builtin_ctzll(bits);
                bits &= bits - 1;
                const int j = b * 64 + q;
                if (USE_WT) {
                    const float4 col = *(const float4*)(WT + (size_t)j * N_NEU + n0);
                    ws[0] += mk2(col.x, col.y);
                    ws[1] += mk2(col.z, col.w);
                } else {
#pragma unroll
                    for (int h = 0; h < NPH; ++h) {
                        ws[h][0] += W[(size_t)(n0 + 2 * h)     * N_NEU + j];
                        ws[h][1] += W[(size_t)(n0 + 2 * h + 1) * N_NEU + j];
                    }
                }
            }
        }

#pragma unroll
        for (int h = 0; h < NPH; ++h) {
            const f32x2 acc = ws[h] + jx[h];
            c[h][0] = c[h][0] + (float)((double)acc[0] * itau[2 * h]);
            c[h][1] = c[h][1] + (float)((double)acc[1] * itau[2 * h + 1]);
        }

        if (t % NB == bid) {
            float4* oV = (float4*)(outV + (size_t)t * N_NEU + n0);
            float4* oC = (float4*)(outC + (size_t)t * N_NEU + n0);
            float4* oS = (float4*)(outS + (size_t)t * N_NEU + n0);
            *oV = make_float4(v[0][0], v[0][1], v[1][0], v[1][1]);
            *oC = make_float4(c[0][0], c[0][1], c[1][0], c[1][1]);
            *oS = make_float4(sv[0][0], sv[0][1], sv[1][0], sv[1][1]);
        }
    };

    for (int t = 0; t < T_STEPS; t += 2) {
        do_step(t,     sA, xA, yA);
        do_step(t + 1, sB, xB, yB);
    }
}

// ---------------------------------------------------------------------------
extern "C" void kernel_launch(void* const* d_in, const int* in_sizes, int n_in,
                              void* d_out, int out_size, void* d_ws, size_t ws_size,
                              hipStream_t stream)
{
    const float* v0     = (const float*)d_in[0];
    const float* c0     = (const float*)d_in[1];
    const float* stim   = (const float*)d_in[2];
    const float* ext    = (const float*)d_in[3];
    const float* W      = (const float*)d_in[4];
    const float* jext   = (const float*)d_in[5];
    const float* taum   = (const float*)d_in[6];
    const float* taus   = (const float*)d_in[7];
    const float* tauref = (const float*)d_in[8];
    const float* thr    = (const float*)d_in[9];
    const float* rst    = (const float*)d_in[10];

    float* outV = (float*)d_out;
    float* outC = outV + (size_t)T_STEPS * N_NEU;
    float* outS = outC + (size_t)T_STEPS * N_NEU;

    const size_t WT_B   = (size_t)N_NEU * N_NEU * sizeof(float);       // 64 MiB
    const size_t ARR_B  = (size_t)T_STEPS * N_NEU * sizeof(float);     // 31.25 MiB
    const size_t NEED_A = WT_B + 3 * ARR_B;

    if (ws_size >= NEED_A) {
        float* WT  = (float*)d_ws;
        float* SPa = (float*)((char*)d_ws + WT_B);
        float* Da  = SPa + (size_t)T_STEPS * N_NEU;
        float* DVa = Da  + (size_t)T_STEPS * N_NEU;
        transpose_kernel<<<dim3(128, 128), dim3(32, 8), 0, stream>>>(W, WT);
        prep_kernel<<<8000, 256, 0, stream>>>(stim, ext, jext, taum, taus,
                                              SPa, Da, DVa);
        lifA_kernel<<<NB, NTHREADS, 0, stream>>>(
            v0, c0, SPa, Da, DVa, WT, taum, taus, tauref, thr, rst,
            outV, outC, outS);
    } else if (ws_size >= WT_B) {
        float* WT = (float*)d_ws;
        transpose_kernel<<<dim3(128, 128), dim3(32, 8), 0, stream>>>(W, WT);
        lif_kernel<true><<<NB, NTHREADS, 0, stream>>>(
            v0, c0, stim, ext, W, WT, jext, taum, taus, tauref, thr, rst,
            outV, outC, outS);
    } else {
        lif_kernel<false><<<NB, NTHREADS, 0, stream>>>(
            v0, c0, stim, ext, W, (const float*)nullptr, jext, taum, taus,
            tauref, thr, rst, outV, outC, outS);
    }
}